// Round 1
// baseline (476.735 us; speedup 1.0000x reference)
//
#include <hip/hip_runtime.h>
#include <hip/hip_bf16.h>

// Problem constants
#define B_   4
#define L_   1024
#define V_   1280
#define NE_  768          // N_EMBD
#define NB_  8            // N_BIN
#define NH_  32           // N_HID
#define NO_  (NB_*NH_)    // 256 = W1 output dim
#define BL_  (B_*L_)      // 4096

// ---------------------------------------------------------------------------
// Kernel 1: X[4096,256] = H[4096,768] @ W1[768,256]   (fp32, tiled)
// 64x64 tile, BK=16, 256 threads, each thread computes 4x4.
// ---------------------------------------------------------------------------
__global__ __launch_bounds__(256) void k1_gemm(const float* __restrict__ H,
                                               const float* __restrict__ W1,
                                               float* __restrict__ X) {
    __shared__ float As[16][64];   // As[k][m]
    __shared__ float Bs[16][64];   // Bs[k][n]

    const int t  = threadIdx.x;
    const int m0 = blockIdx.x * 64;
    const int n0 = blockIdx.y * 64;
    const int tx = t & 15;         // col group
    const int ty = t >> 4;         // row group

    // A-load mapping: 64 rows x 16 cols, one float4 per thread
    const int lr = t >> 2;         // 0..63 row
    const int lq = t & 3;          // quad within 16-wide row
    // B-load mapping: 16 rows x 64 cols, one float4 per thread
    const int br = t >> 4;         // 0..15 row (k)
    const int bq = t & 15;         // quad within 64-wide row

    float acc[4][4];
#pragma unroll
    for (int r = 0; r < 4; ++r)
#pragma unroll
        for (int c = 0; c < 4; ++c) acc[r][c] = 0.0f;

    for (int k0 = 0; k0 < NE_; k0 += 16) {
        float4 av = *(const float4*)(H  + (size_t)(m0 + lr) * NE_ + k0 + lq * 4);
        float4 bv = *(const float4*)(W1 + (size_t)(k0 + br) * NO_ + n0 + bq * 4);
        __syncthreads();           // previous iteration's compute done
        As[lq*4+0][lr] = av.x;
        As[lq*4+1][lr] = av.y;
        As[lq*4+2][lr] = av.z;
        As[lq*4+3][lr] = av.w;
        *(float4*)&Bs[br][bq*4] = bv;
        __syncthreads();
#pragma unroll
        for (int kk = 0; kk < 16; ++kk) {
            float4 a = *(float4*)&As[kk][ty*4];
            float4 b = *(float4*)&Bs[kk][tx*4];
            acc[0][0] += a.x*b.x; acc[0][1] += a.x*b.y; acc[0][2] += a.x*b.z; acc[0][3] += a.x*b.w;
            acc[1][0] += a.y*b.x; acc[1][1] += a.y*b.y; acc[1][2] += a.y*b.z; acc[1][3] += a.y*b.w;
            acc[2][0] += a.z*b.x; acc[2][1] += a.z*b.y; acc[2][2] += a.z*b.z; acc[2][3] += a.z*b.w;
            acc[3][0] += a.w*b.x; acc[3][1] += a.w*b.y; acc[3][2] += a.w*b.z; acc[3][3] += a.w*b.w;
        }
    }
#pragma unroll
    for (int r = 0; r < 4; ++r) {
        float4 v = make_float4(acc[r][0], acc[r][1], acc[r][2], acc[r][3]);
        *(float4*)&X[(size_t)(m0 + ty*4 + r) * NO_ + n0 + tx*4] = v;
    }
}

// ---------------------------------------------------------------------------
// Kernel 2: logits[bl, n, v] = sum_h X[bl, n*32+h] * W2[h, v]
// Block: 4 bl-rows x 256 v-cols. LDS: x tile (4 KB) + W2 tile (32 KB).
// Each wave (64 lanes) owns one bl row; lane owns a v-quad; 8 n's each.
// ---------------------------------------------------------------------------
__global__ __launch_bounds__(256) void k2_logits(const float* __restrict__ X,
                                                 const float* __restrict__ W2,
                                                 float* __restrict__ outL) {
    __shared__ float xs[4 * NO_];        // 4 rows x 256
    __shared__ float w2s[NH_][256];      // 32 x 256

    const int t   = threadIdx.x;
    const int bl0 = blockIdx.x * 4;
    const int v0  = blockIdx.y * 256;

#pragma unroll
    for (int j = 0; j < 4; ++j)
        xs[j * 256 + t] = X[(size_t)bl0 * NO_ + j * 256 + t];
#pragma unroll
    for (int hh = 0; hh < NH_; ++hh)
        w2s[hh][t] = W2[(size_t)hh * V_ + v0 + t];
    __syncthreads();

    const int c4 = (t & 63) * 4;   // v-quad within tile
    const int g  = t >> 6;         // bl row within tile (== wave id)

    float4 acc[NB_];
#pragma unroll
    for (int n = 0; n < NB_; ++n) acc[n] = make_float4(0.f, 0.f, 0.f, 0.f);

#pragma unroll
    for (int hh = 0; hh < NH_; ++hh) {
        float4 w = *(float4*)&w2s[hh][c4];
#pragma unroll
        for (int n = 0; n < NB_; ++n) {
            float xv = xs[g * 256 + n * 32 + hh];   // broadcast within wave
            acc[n].x += xv * w.x;
            acc[n].y += xv * w.y;
            acc[n].z += xv * w.z;
            acc[n].w += xv * w.w;
        }
    }

    const size_t bl = (size_t)(bl0 + g);
#pragma unroll
    for (int n = 0; n < NB_; ++n)
        *(float4*)&outL[(bl * NB_ + n) * V_ + v0 + c4] = acc[n];
}

// ---------------------------------------------------------------------------
// Kernel 3: tte + censor mask.
// token_index[b,i,v] = min{ j : (j>=i && targets[b,j]==v) || (j<i && v==0) }
// (the v==0 clause replicates the reference's where(upper,...,0) scatter).
// Grid: (v_tiles=5, chunks=32, b=4). Block: 256 threads, one v each.
// Each block scans targets[b] from L-1 down to its chunk start (LDS
// broadcast, 2 VALU/step) and emits tte + 8 mask planes for its chunk.
// ---------------------------------------------------------------------------
#define K3_S 32   // i-chunk size

__global__ __launch_bounds__(256) void k3_tte(const float* __restrict__ age,
                                              const float* __restrict__ tage,
                                              const int*   __restrict__ targets,
                                              float* __restrict__ outT,
                                              float* __restrict__ outM) {
    __shared__ int   tg[L_];
    __shared__ float ta[L_];
    __shared__ float ag[K3_S];

    const int t      = threadIdx.x;
    const int v      = blockIdx.x * 256 + t;
    const int istart = blockIdx.y * K3_S;
    const int iend   = istart + K3_S;
    const int b      = blockIdx.z;

    for (int j = t; j < L_; j += 256) {
        tg[j] = targets[(size_t)b * L_ + j];
        ta[j] = tage[(size_t)b * L_ + j];
    }
    if (t < K3_S) ag[t] = age[(size_t)b * L_ + istart + t];
    __syncthreads();

    int cur = L_;   // next occurrence index (L = none)
    for (int i = L_ - 1; i >= istart; --i) {
        const int ti = tg[i];                 // broadcast LDS read
        if (ti == v) cur = i;
        if (i < iend) {
            int idx = cur;
            if (v == 0 && i >= 1) idx = 0;    // reference's j<i scatter into v=0
            const bool noev = (idx == L_);
            const int  ic   = noev ? (L_ - 1) : idx;
            const float tte = ta[ic] - ag[i - istart];

            outT[((size_t)(b * L_ + i)) * V_ + v] = tte;

            const size_t mb = ((size_t)(b * L_ + i)) * NB_ * V_ + v;
#pragma unroll
            for (int n = 0; n < NB_; ++n) {
                const float lo = n * 1.25f;
                const float hi = (n + 1) * 1.25f;
                const bool in_bin = (tte >= lo) && (tte < hi);
                outM[mb + (size_t)n * V_] = (in_bin || noev) ? 1.0f : 0.0f;
            }
        }
    }
}

// ---------------------------------------------------------------------------
extern "C" void kernel_launch(void* const* d_in, const int* in_sizes, int n_in,
                              void* d_out, int out_size, void* d_ws, size_t ws_size,
                              hipStream_t stream) {
    const float* h       = (const float*)d_in[0];   // (4,1024,768)
    const float* age     = (const float*)d_in[1];   // (4,1024)
    const float* tage    = (const float*)d_in[2];   // (4,1024)
    /* d_in[3] = delta_t, unused by outputs */
    const int*   targets = (const int*)  d_in[4];   // (4,1024)
    const float* W1      = (const float*)d_in[5];   // (768,256)
    const float* W2      = (const float*)d_in[6];   // (32,1280)

    float* out  = (float*)d_out;
    float* outL = out;                              // 41943040 = 4*1024*8*1280
    float* outT = out + (size_t)BL_ * NB_ * V_;     // 5242880  = 4*1024*1280
    float* outM = outT + (size_t)BL_ * V_;          // 41943040

    float* X = (float*)d_ws;                        // 4096*256 fp32 = 4 MB scratch

    k1_gemm  <<<dim3(BL_/64, NO_/64), 256, 0, stream>>>(h, W1, X);
    k2_logits<<<dim3(BL_/4, V_/256),  256, 0, stream>>>(X, W2, outL);
    k3_tte   <<<dim3(V_/256, L_/K3_S, B_), 256, 0, stream>>>(age, tage, targets, outT, outM);
}

// Round 2
// 423.089 us; speedup vs baseline: 1.1268x; 1.1268x over previous
//
#include <hip/hip_runtime.h>
#include <hip/hip_bf16.h>

// Problem constants
#define B_   4
#define L_   1024
#define V_   1280
#define NE_  768          // N_EMBD
#define NB_  8            // N_BIN
#define NH_  32           // N_HID
#define NO_  (NB_*NH_)    // 256 = W1 output dim
#define BL_  (B_*L_)      // 4096
#define M2_  (BL_*NB_)    // 32768 = rows of second GEMM

typedef __attribute__((ext_vector_type(8))) short bf16x8;
typedef __attribute__((ext_vector_type(4))) float floatx4;

__device__ __forceinline__ unsigned short f2bf(float f) {
    unsigned int u = __float_as_uint(f);
    u += 0x7FFFu + ((u >> 16) & 1u);      // RNE (inputs are finite, no NaN)
    return (unsigned short)(u >> 16);
}

// ---------------------------------------------------------------------------
// k0: pack h -> bf16 (row-major), W1 -> bf16 TRANSPOSED (256x768),
//     W2 -> bf16 TRANSPOSED (1280x32). Grid-stride over flat work items.
// ---------------------------------------------------------------------------
#define H4_N   (BL_*NE_/4)      // 786432 float4 conversions for h
#define W1T_N  (NO_*NE_)        // 196608
#define W2T_N  (V_*NH_)         // 40960
#define K0_TOT (H4_N + W1T_N + W2T_N)

__global__ __launch_bounds__(256) void k0_pack(const float* __restrict__ h,
                                               const float* __restrict__ W1,
                                               const float* __restrict__ W2,
                                               unsigned short* __restrict__ hb,
                                               unsigned short* __restrict__ W1T,
                                               unsigned short* __restrict__ W2T) {
    int id = blockIdx.x * 256 + threadIdx.x;
    if (id < H4_N) {
        float4 v = ((const float4*)h)[id];
        ushort4 o;
        o.x = f2bf(v.x); o.y = f2bf(v.y); o.z = f2bf(v.z); o.w = f2bf(v.w);
        ((ushort4*)hb)[id] = o;
    } else if (id < H4_N + W1T_N) {
        int j = id - H4_N;          // j = o*768 + k
        int o = j / NE_;
        int k = j - o * NE_;
        W1T[j] = f2bf(W1[(size_t)k * NO_ + o]);
    } else if (id < K0_TOT) {
        int j = id - H4_N - W1T_N;  // j = v*32 + k
        int v = j >> 5;
        int k = j & 31;
        W2T[j] = f2bf(W2[(size_t)k * V_ + v]);
    }
}

// ---------------------------------------------------------------------------
// k1: Xb[4096,256](bf16) = hb[4096,768] @ W1 (via W1T), MFMA 16x16x32 bf16.
// 64x64 tile, 256 threads (4 waves). Wave w computes rows [w*16,w*16+16),
// all 64 cols as 4 n-subtiles. LDS rows padded to 40 bf16 (80 B) so the
// 16-row-strided b128 frag reads spread over all 32 banks (2-way = free).
// Software-pipelined global loads (next tile issued before compute).
// ---------------------------------------------------------------------------
__global__ __launch_bounds__(256) void k1_gemm(const unsigned short* __restrict__ hb,
                                               const unsigned short* __restrict__ W1T,
                                               unsigned short* __restrict__ Xb) {
    __shared__ short A_lds[64][40];   // [row][k] bf16, +8 pad
    __shared__ short Bt_lds[64][40];  // [col][k] bf16, +8 pad

    const int t      = threadIdx.x;
    const int m0     = blockIdx.x * 64;
    const int n0     = blockIdx.y * 64;
    const int l      = t & 63;
    const int w      = t >> 6;
    const int lane15 = l & 15;
    const int quad   = l >> 4;

    // staging map: 256 threads, thread -> (row = t>>2, 8-elem quad q = t&3)
    const int srow = t >> 2;
    const int sq   = (t & 3) * 8;

    const unsigned short* aptr = hb  + (size_t)(m0 + srow) * NE_ + sq;
    const unsigned short* bptr = W1T + (size_t)(n0 + srow) * NE_ + sq;

    floatx4 acc[4];
#pragma unroll
    for (int i = 0; i < 4; ++i) acc[i] = (floatx4){0.f, 0.f, 0.f, 0.f};

    bf16x8 av = *(const bf16x8*)aptr;
    bf16x8 bv = *(const bf16x8*)bptr;

    for (int k0 = 0; k0 < NE_; k0 += 32) {
        __syncthreads();
        *(bf16x8*)&A_lds[srow][sq]  = av;
        *(bf16x8*)&Bt_lds[srow][sq] = bv;
        __syncthreads();
        if (k0 + 32 < NE_) {
            av = *(const bf16x8*)(aptr + k0 + 32);
            bv = *(const bf16x8*)(bptr + k0 + 32);
        }
        bf16x8 af = *(bf16x8*)&A_lds[w * 16 + lane15][quad * 8];
#pragma unroll
        for (int nt = 0; nt < 4; ++nt) {
            bf16x8 bf = *(bf16x8*)&Bt_lds[nt * 16 + lane15][quad * 8];
            acc[nt] = __builtin_amdgcn_mfma_f32_16x16x32_bf16(af, bf, acc[nt], 0, 0, 0);
        }
    }

    // C/D layout: col = lane&15, row = quad*4 + r   (m89/m91-verified)
    const int rbase = m0 + w * 16 + quad * 4;
#pragma unroll
    for (int nt = 0; nt < 4; ++nt)
#pragma unroll
        for (int r = 0; r < 4; ++r)
            Xb[(size_t)(rbase + r) * NO_ + n0 + nt * 16 + lane15] = f2bf(acc[nt][r]);
}

// ---------------------------------------------------------------------------
// k2: logits[32768,1280] = Xb[32768,32] @ W2 (via W2T), one MFMA per tile
// (K=32 in a single 16x16x32). No LDS: A-frag is 16 contiguous bytes of Xb
// per lane; B-frags stream from L2-resident W2T (80 KB).
// Block = 256 threads = 4 waves = 64 rows; each wave loops 80 v-tiles.
// ---------------------------------------------------------------------------
__global__ __launch_bounds__(256) void k2_logits(const unsigned short* __restrict__ Xb,
                                                 const unsigned short* __restrict__ W2T,
                                                 float* __restrict__ outL) {
    const int t      = threadIdx.x;
    const int m0     = blockIdx.x * 64;
    const int l      = t & 63;
    const int w      = t >> 6;
    const int lane15 = l & 15;
    const int quad   = l >> 4;

    const int m = m0 + w * 16 + lane15;
    const bf16x8 af = *(const bf16x8*)(Xb + (size_t)m * NH_ + quad * 8);

    const int rbase = m0 + w * 16 + quad * 4;

#pragma unroll 4
    for (int nt = 0; nt < V_ / 16; ++nt) {
        bf16x8 bf = *(const bf16x8*)(W2T + (size_t)(nt * 16 + lane15) * NH_ + quad * 8);
        floatx4 c = (floatx4){0.f, 0.f, 0.f, 0.f};
        c = __builtin_amdgcn_mfma_f32_16x16x32_bf16(af, bf, c, 0, 0, 0);
#pragma unroll
        for (int r = 0; r < 4; ++r)
            outL[(size_t)(rbase + r) * V_ + nt * 16 + lane15] = c[r];
    }
}

// ---------------------------------------------------------------------------
// k3: tte + censor mask (unchanged from passing round 1).
// ---------------------------------------------------------------------------
#define K3_S 32   // i-chunk size

__global__ __launch_bounds__(256) void k3_tte(const float* __restrict__ age,
                                              const float* __restrict__ tage,
                                              const int*   __restrict__ targets,
                                              float* __restrict__ outT,
                                              float* __restrict__ outM) {
    __shared__ int   tg[L_];
    __shared__ float ta[L_];
    __shared__ float ag[K3_S];

    const int t      = threadIdx.x;
    const int v      = blockIdx.x * 256 + t;
    const int istart = blockIdx.y * K3_S;
    const int iend   = istart + K3_S;
    const int b      = blockIdx.z;

    for (int j = t; j < L_; j += 256) {
        tg[j] = targets[(size_t)b * L_ + j];
        ta[j] = tage[(size_t)b * L_ + j];
    }
    if (t < K3_S) ag[t] = age[(size_t)b * L_ + istart + t];
    __syncthreads();

    int cur = L_;   // next occurrence index (L = none)
    for (int i = L_ - 1; i >= istart; --i) {
        const int ti = tg[i];                 // broadcast LDS read
        if (ti == v) cur = i;
        if (i < iend) {
            int idx = cur;
            if (v == 0 && i >= 1) idx = 0;    // reference's j<i scatter into v=0
            const bool noev = (idx == L_);
            const int  ic   = noev ? (L_ - 1) : idx;
            const float tte = ta[ic] - ag[i - istart];

            outT[((size_t)(b * L_ + i)) * V_ + v] = tte;

            const size_t mb = ((size_t)(b * L_ + i)) * NB_ * V_ + v;
#pragma unroll
            for (int n = 0; n < NB_; ++n) {
                const float lo = n * 1.25f;
                const float hi = (n + 1) * 1.25f;
                const bool in_bin = (tte >= lo) && (tte < hi);
                outM[mb + (size_t)n * V_] = (in_bin || noev) ? 1.0f : 0.0f;
            }
        }
    }
}

// ---------------------------------------------------------------------------
extern "C" void kernel_launch(void* const* d_in, const int* in_sizes, int n_in,
                              void* d_out, int out_size, void* d_ws, size_t ws_size,
                              hipStream_t stream) {
    const float* h       = (const float*)d_in[0];   // (4,1024,768)
    const float* age     = (const float*)d_in[1];   // (4,1024)
    const float* tage    = (const float*)d_in[2];   // (4,1024)
    /* d_in[3] = delta_t, unused by outputs */
    const int*   targets = (const int*)  d_in[4];   // (4,1024)
    const float* W1      = (const float*)d_in[5];   // (768,256)
    const float* W2      = (const float*)d_in[6];   // (32,1280)

    float* out  = (float*)d_out;
    float* outL = out;                              // 4*1024*8*1280
    float* outT = out + (size_t)BL_ * NB_ * V_;
    float* outM = outT + (size_t)BL_ * V_;

    // workspace layout (all 16B-aligned)
    char* ws = (char*)d_ws;
    unsigned short* hb  = (unsigned short*)(ws);                       // 6,291,456 B
    unsigned short* W1T = (unsigned short*)(ws + 6291456);             //   393,216 B
    unsigned short* W2T = (unsigned short*)(ws + 6291456 + 393216);    //    81,920 B
    unsigned short* Xb  = (unsigned short*)(ws + 6291456 + 393216 + 81920); // 2 MB

    k0_pack  <<<(K0_TOT + 255) / 256, 256, 0, stream>>>(h, W1, W2, hb, W1T, W2T);
    k1_gemm  <<<dim3(BL_/64, NO_/64), 256, 0, stream>>>(hb, W1T, Xb);
    k2_logits<<<M2_/64, 256, 0, stream>>>(Xb, W2T, outL);
    k3_tte   <<<dim3(V_/256, L_/K3_S, B_), 256, 0, stream>>>(age, tage, targets, outT, outM);
}